// Round 3
// baseline (330.286 us; speedup 1.0000x reference)
//
#include <hip/hip_runtime.h>
#include <cmath>

#define D_IN 512
#define HC   512   // H1*C1 == H2*C2 == D_IN
#define NH1  8
#define NC1  64
#define NH2  4
#define NC2  128
#define BM 128
#define BN 128
#define BK 64

typedef __attribute__((ext_vector_type(8))) short short8;
typedef __attribute__((ext_vector_type(8))) unsigned short u16x8;
typedef __attribute__((ext_vector_type(4))) float f32x4;

__device__ inline ushort f2bf(float f) {
  unsigned u = __float_as_uint(f);
  return (ushort)((u + 0x7FFFu + ((u >> 16) & 1u)) >> 16);
}
__device__ inline float bf2f(ushort b) { return __uint_as_float(((unsigned)b) << 16); }

// ---------- all input casts + degree histogram in ONE launch ---------------
__global__ void k_pre(const float* __restrict__ x, ushort* __restrict__ Abf,
                      const float* __restrict__ W1, const float* __restrict__ W2,
                      ushort* __restrict__ Wt1, ushort* __restrict__ Wt2, int n4x,
                      const int* __restrict__ ei, int E, int Etot,
                      int* __restrict__ cnt) {
  const int KN = D_IN * HC;
  int i = blockIdx.x * blockDim.x + threadIdx.x;
  if (i < n4x) {
    float4 v = ((const float4*)x)[i];
    ushort4 r = { f2bf(v.x), f2bf(v.y), f2bf(v.z), f2bf(v.w) };
    ((ushort4*)Abf)[i] = r;
  } else if (i < n4x + 2 * KN) {
    int idx = i - n4x;
    const float* W = (idx < KN) ? W1 : W2;
    ushort* Wt = (idx < KN) ? Wt1 : Wt2;
    int j = (idx < KN) ? idx : idx - KN;
    int n = j / D_IN, k = j - n * D_IN;
    Wt[j] = f2bf(W[(size_t)k * HC + n]);
  } else {
    int e = i - n4x - 2 * KN;
    if (e >= Etot) return;
    int d = (e < E) ? ei[E + e] : e - E;
    atomicAdd(&cnt[d], 1);
  }
}

// ---------- bf16 MFMA GEMM, BK=64, fused att epilogue (R0 proven form) -----
// R16: reverted to the R0/287.5us-session structure. The R14/R15 counted-
// vmcnt pipelines bought no measurable total change (GEMM ~14% of total)
// and R15 produced one 20ms outlier dispatch (occ 2%) — unexplained risk,
// removed. LDS layout: slot s=(rowgrp)*4+kchunk, addr=(s*16+ln)*8 ushorts;
// staging thread t -> LDS offset t*8 (wave-uniform base + lane*16B as
// global_load_lds requires); ds_read stride-1 across lanes -> conflict-free
// (verified: SQ_LDS_BANK_CONFLICT=0). Do NOT trade occupancy/grid for
// traffic (BN=512 regressed 42->79 us despite 3.5x lower FETCH).
// Att epilogue: plain stores only. H=8 (C=64): one slot per (row,h).
// H=4 (C=128): two partial slots per (row,h): [(row*4+h)*2+sub], sub=col64.
template<int H>
__global__ void k_gemm_bf16(const ushort* __restrict__ A, const ushort* __restrict__ Bt,
                            ushort* __restrict__ Cbf,
                            const float* __restrict__ att_s, const float* __restrict__ att_d,
                            float* __restrict__ asrc, float* __restrict__ adst, int M) {
  constexpr int C = HC / H;
  __shared__ __align__(16) ushort As[BM * BK];   // 16 KB, two 8KB K-halves
  __shared__ __align__(16) ushort Bs[BN * BK];   // 16 KB
  int t = threadIdx.x;
  int m0 = blockIdx.y * BM;
  int n0 = blockIdx.x * BN;
  int wave = t >> 6, lane = t & 63;
  int ln = lane & 15, qd = lane >> 4;
  int wm = (wave >> 1) * 64, wn = (wave & 1) * 64;

  f32x4 acc[4][4] = {};

  int g = t >> 6, ct = (t >> 4) & 3, lt = t & 15;
  int rA0 = m0 + g * 16 + lt;      if (rA0 > M - 1) rA0 = M - 1;
  int rA1 = m0 + 64 + g * 16 + lt; if (rA1 > M - 1) rA1 = M - 1;
  const ushort* gA0 = A + (size_t)rA0 * D_IN + ct * 8;
  const ushort* gA1 = A + (size_t)rA1 * D_IN + ct * 8;
  const ushort* gB0 = Bt + (size_t)(n0 + g * 16 + lt) * D_IN + ct * 8;
  const ushort* gB1 = Bt + (size_t)(n0 + 64 + g * 16 + lt) * D_IN + ct * 8;

  for (int k0 = 0; k0 < D_IN; k0 += BK) {
    __syncthreads();
#pragma unroll
    for (int h = 0; h < 2; ++h) {
      int ko = k0 + h * 32;
      int lo = h * 4096;
      __builtin_amdgcn_global_load_lds(
          (const __attribute__((address_space(1))) void*)(gA0 + ko),
          (__attribute__((address_space(3))) void*)(As + lo + t * 8), 16, 0, 0);
      __builtin_amdgcn_global_load_lds(
          (const __attribute__((address_space(1))) void*)(gA1 + ko),
          (__attribute__((address_space(3))) void*)(As + lo + 2048 + t * 8), 16, 0, 0);
      __builtin_amdgcn_global_load_lds(
          (const __attribute__((address_space(1))) void*)(gB0 + ko),
          (__attribute__((address_space(3))) void*)(Bs + lo + t * 8), 16, 0, 0);
      __builtin_amdgcn_global_load_lds(
          (const __attribute__((address_space(1))) void*)(gB1 + ko),
          (__attribute__((address_space(3))) void*)(Bs + lo + 2048 + t * 8), 16, 0, 0);
    }
    __syncthreads();
#pragma unroll
    for (int h = 0; h < 2; ++h) {
      int lo = h * 4096;
      short8 a[4], bb[4];
#pragma unroll
      for (int i = 0; i < 4; ++i)
        a[i] = *(const short8*)&As[lo + (((wave >> 1) * 4 + i) * 4 + qd) * 128 + ln * 8];
#pragma unroll
      for (int j = 0; j < 4; ++j)
        bb[j] = *(const short8*)&Bs[lo + (((wave & 1) * 4 + j) * 4 + qd) * 128 + ln * 8];
#pragma unroll
      for (int i = 0; i < 4; ++i)
#pragma unroll
        for (int j = 0; j < 4; ++j)
          acc[i][j] = __builtin_amdgcn_mfma_f32_16x16x32_bf16(a[i], bb[j], acc[i][j], 0, 0, 0);
    }
  }

  // ---- C store (C/D layout: col = ln, row = qd*4 + reg) ----
#pragma unroll
  for (int i = 0; i < 4; ++i) {
#pragma unroll
    for (int reg = 0; reg < 4; ++reg) {
      int row = m0 + wm + i * 16 + qd * 4 + reg;
      if (row >= M) continue;
#pragma unroll
      for (int j = 0; j < 4; ++j)
        Cbf[(size_t)row * HC + n0 + wn + j * 16 + ln] = f2bf(acc[i][j][reg]);
    }
  }

  // ---- fused attention scores (plain stores only) ----
  int colbase = n0 + wn;         // multiple of 64
  int h = colbase / C;
  float sa[4], da[4];
#pragma unroll
  for (int j = 0; j < 4; ++j) {
    int c = (colbase % C) + j * 16 + ln;
    sa[j] = att_s[h * C + c];
    da[j] = att_d[h * C + c];
  }
#pragma unroll
  for (int i = 0; i < 4; ++i) {
#pragma unroll
    for (int reg = 0; reg < 4; ++reg) {
      float ps = acc[i][0][reg] * sa[0] + acc[i][1][reg] * sa[1]
               + acc[i][2][reg] * sa[2] + acc[i][3][reg] * sa[3];
      float pd = acc[i][0][reg] * da[0] + acc[i][1][reg] * da[1]
               + acc[i][2][reg] * da[2] + acc[i][3][reg] * da[3];
#pragma unroll
      for (int o = 1; o < 16; o <<= 1) { ps += __shfl_xor(ps, o); pd += __shfl_xor(pd, o); }
      int row = m0 + wm + i * 16 + qd * 4 + reg;
      if (ln == 0 && row < M) {
        if (C == 64) {
          asrc[row * H + h] = ps; adst[row * H + h] = pd;
        } else {
          int sub = (colbase >> 6) & 1;
          asrc[(row * H + h) * 2 + sub] = ps;
          adst[(row * H + h) * 2 + sub] = pd;
        }
      }
    }
  }
}

// ---------------- CSR build ------------------------------------------------
// single-block scan, thread-serial + shuffle (2 barriers total)
__global__ void k_scan(const int* __restrict__ cnt, int* __restrict__ rowstart, int N) {
  int tid = threadIdx.x;                 // 1024
  int T = (N + 1023) / 1024;
  int base = tid * T;
  int sum = 0;
  for (int i = 0; i < T; ++i) { int j = base + i; if (j < N) sum += cnt[j]; }
  int lane = tid & 63, w = tid >> 6;
  int v = sum;
#pragma unroll
  for (int off = 1; off < 64; off <<= 1) {
    int u = __shfl_up(v, off);
    if (lane >= off) v += u;
  }
  __shared__ int wsum[16];
  if (lane == 63) wsum[w] = v;
  __syncthreads();
  if (tid < 16) {
    int tv = wsum[tid];
#pragma unroll
    for (int off = 1; off < 16; off <<= 1) {
      int u = __shfl_up(tv, off);
      if (tid >= off) tv += u;
    }
    wsum[tid] = tv;
  }
  __syncthreads();
  int wave_prefix = (w == 0) ? 0 : wsum[w - 1];
  int run = wave_prefix + v - sum;       // exclusive prefix for this thread
  for (int i = 0; i < T; ++i) {
    int j = base + i;
    if (j < N) { rowstart[j] = run; run += cnt[j]; }
  }
  if (tid == 1023) rowstart[N] = run;
}

__global__ void k_scatter(const int* __restrict__ ei, int E, int Etot,
                          const int* __restrict__ rowstart, int* __restrict__ cursor,
                          int* __restrict__ csr_src) {
  int e = blockIdx.x * blockDim.x + threadIdx.x;
  if (e >= Etot) return;
  int s = (e < E) ? ei[e] : e - E;
  int d = (e < E) ? ei[E + e] : e - E;
  int pos = atomicAdd(&cursor[d], 1);
  csr_src[rowstart[d] + pos] = s;
}

// -------- layer-1 aggregation, CHANNEL-SLICED for L2 locality (R16) --------
// R0 (128thr/node) and R14 (wave/node) both pinned at 41.7us with all pipes
// <35%: the random 1KB-row gather over the 20.5MB xp table misses the 4MB
// per-XCD L2 (FETCH=62MB = 3x table). Fix: slice channels. Layer-1 output
// chan h*64+c depends only on xp chans [h*64,h*64+64) (slice==head, C1=64).
// One wave per (node, slice); slice = blockIdx.x & 7 -> blocks round-robin
// XCDs by linear id, so XCD i only touches slice i: 20K x 128B = 2.56MB
// working set, fits its L2 -> gathers become L2 hits. Per edge per wave:
// one WAVE-UNIFORM score load + one contiguous 128B line (lane=chan, 2B).
// wsum is uniform -> no reduction. If the CP maps blocks chunked instead of
// round-robin this degrades gracefully to today's locality (correct either
// way). hout row written by 8 blocks, 128B disjoint chunks each.
__global__ void k_agg1(const int* __restrict__ rowstart, const int* __restrict__ csr_src,
                       const float* __restrict__ asrc, const float* __restrict__ adst,
                       const ushort* __restrict__ xp, ushort* __restrict__ hout,
                       const float* __restrict__ bias, int N) {
  int wv = threadIdx.x >> 6, lane = threadIdx.x & 63;
  int s = blockIdx.x & 7;                   // slice == head, pinned per XCD
  int n = (blockIdx.x >> 3) * 4 + wv;
  if (n >= N) return;                       // wave-uniform
  int beg = rowstart[n], end = rowstart[n + 1];
  float adn = adst[n * NH1 + s];
  const ushort* xs = xp + (size_t)s * NC1 + lane;   // + src*HC per edge

  float accv = 0.f, wsum = 0.f;
  for (int c0 = beg; c0 < end; c0 += 64) {
    int len = end - c0; if (len > 64) len = 64;
    int ev = (lane < len) ? csr_src[c0 + lane] : 0;
    int j = 0;
    for (; j + 1 < len; j += 2) {
      int s0 = __shfl(ev, j), s1 = __shfl(ev, j + 1);
      float v0 = asrc[s0 * NH1 + s] + adn;    // wave-uniform
      float v1 = asrc[s1 * NH1 + s] + adn;
      ushort x0 = xs[(size_t)s0 * HC];        // 64 lanes = one 128B line
      ushort x1 = xs[(size_t)s1 * HC];
      v0 = (v0 > 0.f) ? v0 : 0.2f * v0;
      v1 = (v1 > 0.f) ? v1 : 0.2f * v1;
      float w0 = __expf(v0), w1 = __expf(v1);
      accv += w0 * bf2f(x0) + w1 * bf2f(x1);
      wsum += w0 + w1;
    }
    if (j < len) {
      int s0 = __shfl(ev, j);
      float v0 = asrc[s0 * NH1 + s] + adn;
      ushort x0 = xs[(size_t)s0 * HC];
      v0 = (v0 > 0.f) ? v0 : 0.2f * v0;
      float w0 = __expf(v0);
      accv += w0 * bf2f(x0);
      wsum += w0;
    }
  }
  float v = accv / (wsum + 1e-16f) + bias[s * NC1 + lane];
  v = (v > 0.f) ? v : expm1f(v);            // elu
  hout[(size_t)n * HC + s * NC1 + lane] = f2bf(v);
}

// -------- layer-2 aggregation, ONE WAVE PER NODE (R14 form) ----------------
// scores are 2 partials at [(x*H+h)*2+{0,1}]; head-mean via shfl_xor(16,32)
// fold; fused CE via 16-lane butterflies. No max-subtraction (scores O(1)).
__global__ void k_agg2(const int* __restrict__ rowstart, const int* __restrict__ csr_src,
                       const float* __restrict__ asrc, const float* __restrict__ adst,
                       const ushort* __restrict__ xp,
                       float* __restrict__ out2, const float* __restrict__ bias,
                       const int* __restrict__ y, const int* __restrict__ msk,
                       float* __restrict__ acc2, int N) {
  constexpr int H = NH2;
  int wv = threadIdx.x >> 6, lane = threadIdx.x & 63;
  int n = blockIdx.x * 4 + wv;
  if (n >= N) return;                         // wave-uniform
  int h = lane >> 4;                          // 8 chans/lane
  int beg = rowstart[n], end = rowstart[n + 1];

  float2 t2 = ((const float2*)adst)[n * H + h];
  float adn = t2.x + t2.y;

  float acc[8] = {};
  float wsum = 0.f;

  for (int c0 = beg; c0 < end; c0 += 64) {
    int len = end - c0; if (len > 64) len = 64;
    int ev = (lane < len) ? csr_src[c0 + lane] : 0;
    int j = 0;
    for (; j + 1 < len; j += 2) {
      int s0 = __shfl(ev, j), s1 = __shfl(ev, j + 1);
      float2 p0 = ((const float2*)asrc)[s0 * H + h];
      float2 p1 = ((const float2*)asrc)[s1 * H + h];
      float v0 = p0.x + p0.y + adn;
      float v1 = p1.x + p1.y + adn;
      u16x8 a0 = ((const u16x8*)xp)[(size_t)s0 * 64 + lane];
      u16x8 a1 = ((const u16x8*)xp)[(size_t)s1 * 64 + lane];
      v0 = (v0 > 0.f) ? v0 : 0.2f * v0;
      v1 = (v1 > 0.f) ? v1 : 0.2f * v1;
      float w0 = __expf(v0), w1 = __expf(v1);
#pragma unroll
      for (int k = 0; k < 8; ++k)
        acc[k] += w0 * bf2f(a0[k]) + w1 * bf2f(a1[k]);
      wsum += w0 + w1;
    }
    if (j < len) {
      int s0 = __shfl(ev, j);
      float2 p0 = ((const float2*)asrc)[s0 * H + h];
      float v0 = p0.x + p0.y + adn;
      u16x8 a0 = ((const u16x8*)xp)[(size_t)s0 * 64 + lane];
      v0 = (v0 > 0.f) ? v0 : 0.2f * v0;
      float w0 = __expf(v0);
#pragma unroll
      for (int k = 0; k < 8; ++k) acc[k] += w0 * bf2f(a0[k]);
      wsum += w0;
    }
  }
  float rdn = 1.0f / (wsum + 1e-16f);
#pragma unroll
  for (int k = 0; k < 8; ++k) acc[k] *= rdn;

  // head-mean: channel c'=(lane&15)*8+k lives on lanes {l, l^16, l^32, l^48}
#pragma unroll
  for (int k = 0; k < 8; ++k) {
    float v = acc[k];
    v += __shfl_xor(v, 16);
    v += __shfl_xor(v, 32);
    acc[k] = v * 0.25f + bias[(lane & 15) * 8 + k];
  }
  if (lane < 16) {       // scalar stores: out2 = out+1 is only 4B-aligned
    int cb = lane * 8;
#pragma unroll
    for (int k = 0; k < 8; ++k) out2[(size_t)n * NC2 + cb + k] = acc[k];
  }
  // fused CE: lanes 0..15 hold the 128 logits (copies in upper 48 lanes)
  float mx = acc[0];
#pragma unroll
  for (int k = 1; k < 8; ++k) mx = fmaxf(mx, acc[k]);
#pragma unroll
  for (int o = 1; o < 16; o <<= 1) mx = fmaxf(mx, __shfl_xor(mx, o));
  float e = 0.f;
#pragma unroll
  for (int k = 0; k < 8; ++k) e += __expf(acc[k] - mx);
#pragma unroll
  for (int o = 1; o < 16; o <<= 1) e += __shfl_xor(e, o);
  int yv = y[n];
  float sel = acc[0];
#pragma unroll
  for (int k = 1; k < 8; ++k) sel = ((yv & 7) == k) ? acc[k] : sel;
  float vy = __shfl(sel, yv >> 3);
  if (lane == 0 && msk[n] != 0) {
    float ce = mx + logf(e) - vy;
    int slot = n & 127;
    atomicAdd(&acc2[slot], ce);
    atomicAdd(&acc2[128 + slot], 1.0f);
  }
}

__global__ void k_final(const float* __restrict__ acc2, float* __restrict__ out0) {
  int tid = threadIdx.x;   // 128 threads
  float ce = acc2[tid], ct = acc2[128 + tid];
#pragma unroll
  for (int o = 32; o > 0; o >>= 1) { ce += __shfl_xor(ce, o); ct += __shfl_xor(ct, o); }
  __shared__ float s[4];
  if ((tid & 63) == 0) { s[(tid >> 6) * 2] = ce; s[(tid >> 6) * 2 + 1] = ct; }
  __syncthreads();
  if (tid == 0) out0[0] = (s[0] + s[2]) / (s[1] + s[3]);
}

extern "C" void kernel_launch(void* const* d_in, const int* in_sizes, int n_in,
                              void* d_out, int out_size, void* d_ws, size_t ws_size,
                              hipStream_t stream) {
  const float* x   = (const float*)d_in[0];
  const int*   ei  = (const int*)d_in[1];
  const int*   y   = (const int*)d_in[2];
  const int*   msk = (const int*)d_in[3];
  const float* W1  = (const float*)d_in[4];
  const float* as1 = (const float*)d_in[5];
  const float* ad1 = (const float*)d_in[6];
  const float* b1  = (const float*)d_in[7];
  const float* W2  = (const float*)d_in[8];
  const float* as2 = (const float*)d_in[9];
  const float* ad2 = (const float*)d_in[10];
  const float* b2  = (const float*)d_in[11];
  float* out = (float*)d_out;

  int N = in_sizes[0] / D_IN;   // 20000
  int E = in_sizes[1] / 2;      // 100000
  int Etot = E + N;             // 120000 (self-loops appended)

  float* ws = (float*)d_ws;
  size_t NF = (size_t)N * HC;
  float* asr1 = ws;                       // N*8  (plain-written in GEMM1)
  float* adt1 = asr1 + (size_t)N * NH1;   // N*8
  float* asr2 = adt1 + (size_t)N * NH1;   // N*8  (partials, plain-written GEMM2)
  float* adt2 = asr2 + (size_t)N * 2 * NH2; // N*8
  // ---- zero-init region: acc2, cnt, cursor (contiguous) ----
  float* acc2 = adt2 + (size_t)N * 2 * NH2; // 256
  int*   cnt    = (int*)(acc2 + 256);     // N
  int*   cursor = cnt + N;                // N
  size_t zero_bytes = (256 + 2 * (size_t)N) * sizeof(float);
  // ---- fully-written region ----
  int*   rowstart = cursor + N;           // N+1
  int*   csr_src  = rowstart + N + 1;     // Etot
  ushort* xpbf = (ushort*)((((uintptr_t)(csr_src + Etot)) + 15) & ~(uintptr_t)15);
  ushort* Abf = xpbf + NF;                // N*512
  ushort* Wt1 = Abf + NF;                 // 512*512
  ushort* Wt2 = Wt1 + (size_t)D_IN * HC;  // 512*512

  hipMemsetAsync(acc2, 0, zero_bytes, stream);

  // casts (x, W1^T, W2^T) + degree histogram in one launch
  int n4x = (int)(NF / 4);
  int pre_total = n4x + 2 * D_IN * HC + Etot;
  k_pre<<<(pre_total + 255) / 256, 256, 0, stream>>>(x, Abf, W1, W2, Wt1, Wt2, n4x,
                                                     ei, E, Etot, cnt);

  // CSR build (shared by both layers)
  k_scan<<<1, 1024, 0, stream>>>(cnt, rowstart, N);
  k_scatter<<<(Etot + 255) / 256, 256, 0, stream>>>(ei, E, Etot, rowstart, cursor, csr_src);

  dim3 ggrid(HC / BN, (N + BM - 1) / BM);   // 4 x 157
  int agg1blocks = 8 * ((N + 3) / 4);       // (node x slice) waves, slice = bid&7
  int agg2blocks = (N + 3) / 4;             // 4 nodes (waves) per block

  // ---- layer 1 ----
  k_gemm_bf16<NH1><<<ggrid, 256, 0, stream>>>(Abf, Wt1, xpbf, as1, ad1, asr1, adt1, N);
  k_agg1<<<agg1blocks, 256, 0, stream>>>(rowstart, csr_src, asr1, adt1, xpbf, Abf, b1, N);

  // ---- layer 2 ----
  k_gemm_bf16<NH2><<<ggrid, 256, 0, stream>>>(Abf, Wt2, xpbf, as2, ad2, asr2, adt2, N);
  k_agg2<<<agg2blocks, 256, 0, stream>>>(rowstart, csr_src, asr2, adt2, xpbf,
                                         out + 1, b2, y, msk, acc2, N);

  // ---- epilogue: loss ----
  k_final<<<1, 128, 0, stream>>>(acc2, out);
}

// Round 4
// 292.620 us; speedup vs baseline: 1.1287x; 1.1287x over previous
//
#include <hip/hip_runtime.h>
#include <cmath>

#define D_IN 512
#define HC   512   // H1*C1 == H2*C2 == D_IN
#define NH1  8
#define NC1  64
#define NH2  4
#define NC2  128
#define BM 128
#define BN 128
#define BK 64

typedef __attribute__((ext_vector_type(8))) short short8;
typedef __attribute__((ext_vector_type(8))) unsigned short u16x8;
typedef __attribute__((ext_vector_type(4))) float f32x4;

__device__ inline ushort f2bf(float f) {
  unsigned u = __float_as_uint(f);
  return (ushort)((u + 0x7FFFu + ((u >> 16) & 1u)) >> 16);
}
__device__ inline float bf2f(ushort b) { return __uint_as_float(((unsigned)b) << 16); }

// ---------- all input casts + degree histogram in ONE launch ---------------
__global__ void k_pre(const float* __restrict__ x, ushort* __restrict__ Abf,
                      const float* __restrict__ W1, const float* __restrict__ W2,
                      ushort* __restrict__ Wt1, ushort* __restrict__ Wt2, int n4x,
                      const int* __restrict__ ei, int E, int Etot,
                      int* __restrict__ cnt) {
  const int KN = D_IN * HC;
  int i = blockIdx.x * blockDim.x + threadIdx.x;
  if (i < n4x) {
    float4 v = ((const float4*)x)[i];
    ushort4 r = { f2bf(v.x), f2bf(v.y), f2bf(v.z), f2bf(v.w) };
    ((ushort4*)Abf)[i] = r;
  } else if (i < n4x + 2 * KN) {
    int idx = i - n4x;
    const float* W = (idx < KN) ? W1 : W2;
    ushort* Wt = (idx < KN) ? Wt1 : Wt2;
    int j = (idx < KN) ? idx : idx - KN;
    int n = j / D_IN, k = j - n * D_IN;
    Wt[j] = f2bf(W[(size_t)k * HC + n]);
  } else {
    int e = i - n4x - 2 * KN;
    if (e >= Etot) return;
    int d = (e < E) ? ei[E + e] : e - E;
    atomicAdd(&cnt[d], 1);
  }
}

// ---------- bf16 MFMA GEMM (R0 proven form) + fused scan block (R17) -------
// R17 changes vs R0 form:
//  (a) grid flattened to 1D; when SCAN!=0, block 0 runs the 256-thread CSR
//      prefix scan (gemm1 ⊥ scan, both depend only on k_pre) -> removes the
//      single-block k_scan launch (~10us GPU-wide idle + one gap).
//  (b) chunked bijective XCD swizzle (m204): CP assigns blocks to XCDs
//      round-robin by id; remap so each XCD owns a CONTIGUOUS wg range ->
//      the 4 wg sharing an A row-panel land on one XCD, A HBM refetch
//      ~4x -> ~1x. Isolated change this round (R14/R15 pipeline removed:
//      caused a 20ms outlier dispatch, occ 2% — unexplained risk).
// LDS layout: slot s=(rowgrp)*4+kchunk, addr=(s*16+ln)*8 ushorts; staging
// thread t -> LDS offset t*8 (wave-uniform base + lane*16B as
// global_load_lds requires); ds_read stride-1 across lanes -> conflict-free
// (verified: SQ_LDS_BANK_CONFLICT=0). Do NOT trade occupancy/grid for
// traffic (BN=512 regressed 42->79 us despite 3.5x lower FETCH).
// Att epilogue: plain stores only. H=8 (C=64): one slot per (row,h).
// H=4 (C=128): two partial slots per (row,h): [(row*4+h)*2+sub], sub=col64.
template<int H, int SCAN>
__global__ void k_gemm_bf16(const ushort* __restrict__ A, const ushort* __restrict__ Bt,
                            ushort* __restrict__ Cbf,
                            const float* __restrict__ att_s, const float* __restrict__ att_d,
                            float* __restrict__ asrc, float* __restrict__ adst, int M,
                            const int* __restrict__ cnt, int* __restrict__ rowstart, int Nn) {
  constexpr int C = HC / H;
  __shared__ __align__(16) ushort As[BM * BK];   // 16 KB, two 8KB K-halves
  __shared__ __align__(16) ushort Bs[BN * BK];   // 16 KB
  int t = threadIdx.x;

  if (SCAN && blockIdx.x == 0) {
    // ---- 256-thread exclusive prefix scan: cnt[0..Nn) -> rowstart ----
    __shared__ int wsum[4];
    int T = (Nn + 255) / 256;
    int base = t * T;
    int sum = 0;
    for (int i = 0; i < T; ++i) { int j = base + i; if (j < Nn) sum += cnt[j]; }
    int lane = t & 63, w = t >> 6;
    int v = sum;
#pragma unroll
    for (int off = 1; off < 64; off <<= 1) {
      int u = __shfl_up(v, off);
      if (lane >= off) v += u;
    }
    if (lane == 63) wsum[w] = v;
    __syncthreads();
    int wp = 0;
    for (int i = 0; i < w; ++i) wp += wsum[i];
    int run = wp + v - sum;                 // exclusive prefix for this thread
    for (int i = 0; i < T; ++i) {
      int j = base + i;
      if (j < Nn) { rowstart[j] = run; run += cnt[j]; }
    }
    if (t == 255) rowstart[Nn] = run;
    return;
  }

  int lin = blockIdx.x - (SCAN ? 1 : 0);
  int nwg = gridDim.x - (SCAN ? 1 : 0);     // 628
  // chunked bijective XCD swizzle: round-robin-assigned blocks -> contiguous
  // wg chunk per XCD (consecutive wg share the A panel)
  int q = nwg >> 3, r = nwg & 7;
  int xcd = lin & 7, pos = lin >> 3;
  int wg = (xcd < r ? xcd * (q + 1) : r * (q + 1) + (xcd - r) * q) + pos;
  int m0 = (wg >> 2) * BM;                  // 4 n-tiles per m-panel
  int n0 = (wg & 3) * BN;

  int wave = t >> 6, lane = t & 63;
  int ln = lane & 15, qd = lane >> 4;
  int wm = (wave >> 1) * 64, wn = (wave & 1) * 64;

  f32x4 acc[4][4] = {};

  int g = t >> 6, ct = (t >> 4) & 3, lt = t & 15;
  int rA0 = m0 + g * 16 + lt;      if (rA0 > M - 1) rA0 = M - 1;
  int rA1 = m0 + 64 + g * 16 + lt; if (rA1 > M - 1) rA1 = M - 1;
  const ushort* gA0 = A + (size_t)rA0 * D_IN + ct * 8;
  const ushort* gA1 = A + (size_t)rA1 * D_IN + ct * 8;
  const ushort* gB0 = Bt + (size_t)(n0 + g * 16 + lt) * D_IN + ct * 8;
  const ushort* gB1 = Bt + (size_t)(n0 + 64 + g * 16 + lt) * D_IN + ct * 8;

  for (int k0 = 0; k0 < D_IN; k0 += BK) {
    __syncthreads();
#pragma unroll
    for (int h = 0; h < 2; ++h) {
      int ko = k0 + h * 32;
      int lo = h * 4096;
      __builtin_amdgcn_global_load_lds(
          (const __attribute__((address_space(1))) void*)(gA0 + ko),
          (__attribute__((address_space(3))) void*)(As + lo + t * 8), 16, 0, 0);
      __builtin_amdgcn_global_load_lds(
          (const __attribute__((address_space(1))) void*)(gA1 + ko),
          (__attribute__((address_space(3))) void*)(As + lo + 2048 + t * 8), 16, 0, 0);
      __builtin_amdgcn_global_load_lds(
          (const __attribute__((address_space(1))) void*)(gB0 + ko),
          (__attribute__((address_space(3))) void*)(Bs + lo + t * 8), 16, 0, 0);
      __builtin_amdgcn_global_load_lds(
          (const __attribute__((address_space(1))) void*)(gB1 + ko),
          (__attribute__((address_space(3))) void*)(Bs + lo + 2048 + t * 8), 16, 0, 0);
    }
    __syncthreads();
#pragma unroll
    for (int h = 0; h < 2; ++h) {
      int lo = h * 4096;
      short8 a[4], bb[4];
#pragma unroll
      for (int i = 0; i < 4; ++i)
        a[i] = *(const short8*)&As[lo + (((wave >> 1) * 4 + i) * 4 + qd) * 128 + ln * 8];
#pragma unroll
      for (int j = 0; j < 4; ++j)
        bb[j] = *(const short8*)&Bs[lo + (((wave & 1) * 4 + j) * 4 + qd) * 128 + ln * 8];
#pragma unroll
      for (int i = 0; i < 4; ++i)
#pragma unroll
        for (int j = 0; j < 4; ++j)
          acc[i][j] = __builtin_amdgcn_mfma_f32_16x16x32_bf16(a[i], bb[j], acc[i][j], 0, 0, 0);
    }
  }

  // ---- C store (C/D layout: col = ln, row = qd*4 + reg) ----
#pragma unroll
  for (int i = 0; i < 4; ++i) {
#pragma unroll
    for (int reg = 0; reg < 4; ++reg) {
      int row = m0 + wm + i * 16 + qd * 4 + reg;
      if (row >= M) continue;
#pragma unroll
      for (int j = 0; j < 4; ++j)
        Cbf[(size_t)row * HC + n0 + wn + j * 16 + ln] = f2bf(acc[i][j][reg]);
    }
  }

  // ---- fused attention scores (plain stores only) ----
  int colbase = n0 + wn;         // multiple of 64
  int h = colbase / C;
  float sa[4], da[4];
#pragma unroll
  for (int j = 0; j < 4; ++j) {
    int c = (colbase % C) + j * 16 + ln;
    sa[j] = att_s[h * C + c];
    da[j] = att_d[h * C + c];
  }
#pragma unroll
  for (int i = 0; i < 4; ++i) {
#pragma unroll
    for (int reg = 0; reg < 4; ++reg) {
      float ps = acc[i][0][reg] * sa[0] + acc[i][1][reg] * sa[1]
               + acc[i][2][reg] * sa[2] + acc[i][3][reg] * sa[3];
      float pd = acc[i][0][reg] * da[0] + acc[i][1][reg] * da[1]
               + acc[i][2][reg] * da[2] + acc[i][3][reg] * da[3];
#pragma unroll
      for (int o = 1; o < 16; o <<= 1) { ps += __shfl_xor(ps, o); pd += __shfl_xor(pd, o); }
      int row = m0 + wm + i * 16 + qd * 4 + reg;
      if (ln == 0 && row < M) {
        if (C == 64) {
          asrc[row * H + h] = ps; adst[row * H + h] = pd;
        } else {
          int sub = (colbase >> 6) & 1;
          asrc[(row * H + h) * 2 + sub] = ps;
          adst[(row * H + h) * 2 + sub] = pd;
        }
      }
    }
  }
}

__global__ void k_scatter(const int* __restrict__ ei, int E, int Etot,
                          const int* __restrict__ rowstart, int* __restrict__ cursor,
                          int* __restrict__ csr_src) {
  int e = blockIdx.x * blockDim.x + threadIdx.x;
  if (e >= Etot) return;
  int s = (e < E) ? ei[e] : e - E;
  int d = (e < E) ? ei[E + e] : e - E;
  int pos = atomicAdd(&cursor[d], 1);
  csr_src[rowstart[d] + pos] = s;
}

// -------- gather aggregation, ONE WAVE PER NODE, 4-way unroll (R17) --------
// R3's sliced form regressed (VALU-bound 65%, L2-residency theory failed:
// FETCH went UP). Reverted to R2 wave-per-node form; added 4-way edge
// unroll (4 rows in flight/wave) to test whether per-wave MLP is the agg
// limiter. If agg returns at exactly ~42us, the wall is the global random
// line service rate and agg structure is done.
// MODE 1 (H=8): scores at [x*H+h]; hout = bf16(elu(sum/den + b)).
// MODE 2 (H=4): scores are 2 partials at [(x*H+h)*2+{0,1}];
//   head-mean via shfl_xor(16,32) fold; fused CE via 16-lane butterflies.
template<int H, int MODE>
__global__ void k_agg(const int* __restrict__ rowstart, const int* __restrict__ csr_src,
                      const float* __restrict__ asrc, const float* __restrict__ adst,
                      const ushort* __restrict__ xp, ushort* __restrict__ hout,
                      float* __restrict__ out2, const float* __restrict__ bias,
                      const int* __restrict__ y, const int* __restrict__ msk,
                      float* __restrict__ acc2, int N) {
  int wv = threadIdx.x >> 6, lane = threadIdx.x & 63;
  int n = blockIdx.x * 4 + wv;
  if (n >= N) return;                         // wave-uniform
  int h = (MODE == 1) ? (lane >> 3) : (lane >> 4);   // 8 chans/lane
  int beg = rowstart[n], end = rowstart[n + 1];

  float adn;
  if (MODE == 1) adn = adst[n * H + h];
  else { float2 t2 = ((const float2*)adst)[n * H + h]; adn = t2.x + t2.y; }

  float acc[8] = {};
  float wsum = 0.f;

#define SCR(s_)  ((MODE == 1) ? asrc[(s_) * H + h] \
                   : (((const float2*)asrc)[(s_) * H + h].x + \
                      ((const float2*)asrc)[(s_) * H + h].y))
#define EDGE(w_, a_)  do {                                   \
    float ww = (w_);                                         \
    _Pragma("unroll") for (int k = 0; k < 8; ++k)            \
      acc[k] += ww * bf2f((a_)[k]);                          \
    wsum += ww; } while (0)
#define LRELU(v_) ((v_) > 0.f ? (v_) : 0.2f * (v_))

  for (int c0 = beg; c0 < end; c0 += 64) {
    int len = end - c0; if (len > 64) len = 64;
    int ev = (lane < len) ? csr_src[c0 + lane] : 0;
    int j = 0;
    for (; j + 3 < len; j += 4) {
      int s0 = __shfl(ev, j), s1 = __shfl(ev, j + 1);
      int s2 = __shfl(ev, j + 2), s3 = __shfl(ev, j + 3);
      float v0 = SCR(s0) + adn, v1 = SCR(s1) + adn;
      float v2 = SCR(s2) + adn, v3 = SCR(s3) + adn;
      u16x8 a0 = ((const u16x8*)xp)[(size_t)s0 * 64 + lane];
      u16x8 a1 = ((const u16x8*)xp)[(size_t)s1 * 64 + lane];
      u16x8 a2 = ((const u16x8*)xp)[(size_t)s2 * 64 + lane];
      u16x8 a3 = ((const u16x8*)xp)[(size_t)s3 * 64 + lane];
      EDGE(__expf(LRELU(v0)), a0);
      EDGE(__expf(LRELU(v1)), a1);
      EDGE(__expf(LRELU(v2)), a2);
      EDGE(__expf(LRELU(v3)), a3);
    }
    for (; j + 1 < len; j += 2) {
      int s0 = __shfl(ev, j), s1 = __shfl(ev, j + 1);
      float v0 = SCR(s0) + adn, v1 = SCR(s1) + adn;
      u16x8 a0 = ((const u16x8*)xp)[(size_t)s0 * 64 + lane];
      u16x8 a1 = ((const u16x8*)xp)[(size_t)s1 * 64 + lane];
      EDGE(__expf(LRELU(v0)), a0);
      EDGE(__expf(LRELU(v1)), a1);
    }
    if (j < len) {
      int s0 = __shfl(ev, j);
      float v0 = SCR(s0) + adn;
      u16x8 a0 = ((const u16x8*)xp)[(size_t)s0 * 64 + lane];
      EDGE(__expf(LRELU(v0)), a0);
    }
  }
#undef SCR
#undef EDGE
#undef LRELU

  float rdn = 1.0f / (wsum + 1e-16f);
#pragma unroll
  for (int k = 0; k < 8; ++k) acc[k] *= rdn;

  if (MODE == 1) {
    int c = lane * 8;
    u16x8 rr;
#pragma unroll
    for (int k = 0; k < 8; ++k) {
      float v = acc[k] + bias[c + k];
      v = (v > 0.f) ? v : expm1f(v);
      rr[k] = f2bf(v);
    }
    ((u16x8*)hout)[(size_t)n * 64 + lane] = rr;
  } else {
    // head-mean: channel c'=(lane&15)*8+k lives on lanes {l, l^16, l^32, l^48}
#pragma unroll
    for (int k = 0; k < 8; ++k) {
      float v = acc[k];
      v += __shfl_xor(v, 16);
      v += __shfl_xor(v, 32);
      acc[k] = v * 0.25f + bias[(lane & 15) * 8 + k];
    }
    if (lane < 16) {       // scalar stores: out2 = out+1 is only 4B-aligned
      int cb = lane * 8;
#pragma unroll
      for (int k = 0; k < 8; ++k) out2[(size_t)n * NC2 + cb + k] = acc[k];
    }
    // fused CE: lanes 0..15 hold the 128 logits (copies in upper 48 lanes)
    float mx = acc[0];
#pragma unroll
    for (int k = 1; k < 8; ++k) mx = fmaxf(mx, acc[k]);
#pragma unroll
    for (int o = 1; o < 16; o <<= 1) mx = fmaxf(mx, __shfl_xor(mx, o));
    float e = 0.f;
#pragma unroll
    for (int k = 0; k < 8; ++k) e += __expf(acc[k] - mx);
#pragma unroll
    for (int o = 1; o < 16; o <<= 1) e += __shfl_xor(e, o);
    int yv = y[n];
    float sel = acc[0];
#pragma unroll
    for (int k = 1; k < 8; ++k) sel = ((yv & 7) == k) ? acc[k] : sel;
    float vy = __shfl(sel, yv >> 3);
    if (lane == 0 && msk[n] != 0) {
      float ce = mx + logf(e) - vy;
      int slot = n & 127;
      atomicAdd(&acc2[slot], ce);
      atomicAdd(&acc2[128 + slot], 1.0f);
    }
  }
}

__global__ void k_final(const float* __restrict__ acc2, float* __restrict__ out0) {
  int tid = threadIdx.x;   // 128 threads
  float ce = acc2[tid], ct = acc2[128 + tid];
#pragma unroll
  for (int o = 32; o > 0; o >>= 1) { ce += __shfl_xor(ce, o); ct += __shfl_xor(ct, o); }
  __shared__ float s[4];
  if ((tid & 63) == 0) { s[(tid >> 6) * 2] = ce; s[(tid >> 6) * 2 + 1] = ct; }
  __syncthreads();
  if (tid == 0) out0[0] = (s[0] + s[2]) / (s[1] + s[3]);
}

extern "C" void kernel_launch(void* const* d_in, const int* in_sizes, int n_in,
                              void* d_out, int out_size, void* d_ws, size_t ws_size,
                              hipStream_t stream) {
  const float* x   = (const float*)d_in[0];
  const int*   ei  = (const int*)d_in[1];
  const int*   y   = (const int*)d_in[2];
  const int*   msk = (const int*)d_in[3];
  const float* W1  = (const float*)d_in[4];
  const float* as1 = (const float*)d_in[5];
  const float* ad1 = (const float*)d_in[6];
  const float* b1  = (const float*)d_in[7];
  const float* W2  = (const float*)d_in[8];
  const float* as2 = (const float*)d_in[9];
  const float* ad2 = (const float*)d_in[10];
  const float* b2  = (const float*)d_in[11];
  float* out = (float*)d_out;

  int N = in_sizes[0] / D_IN;   // 20000
  int E = in_sizes[1] / 2;      // 100000
  int Etot = E + N;             // 120000 (self-loops appended)

  float* ws = (float*)d_ws;
  size_t NF = (size_t)N * HC;
  float* asr1 = ws;                       // N*8  (plain-written in GEMM1)
  float* adt1 = asr1 + (size_t)N * NH1;   // N*8
  float* asr2 = adt1 + (size_t)N * NH1;   // N*8  (partials, plain-written GEMM2)
  float* adt2 = asr2 + (size_t)N * 2 * NH2; // N*8
  // ---- zero-init region: acc2, cnt, cursor (contiguous) ----
  float* acc2 = adt2 + (size_t)N * 2 * NH2; // 256
  int*   cnt    = (int*)(acc2 + 256);     // N
  int*   cursor = cnt + N;                // N
  size_t zero_bytes = (256 + 2 * (size_t)N) * sizeof(float);
  // ---- fully-written region ----
  int*   rowstart = cursor + N;           // N+1
  int*   csr_src  = rowstart + N + 1;     // Etot
  ushort* xpbf = (ushort*)((((uintptr_t)(csr_src + Etot)) + 15) & ~(uintptr_t)15);
  ushort* Abf = xpbf + NF;                // N*512
  ushort* Wt1 = Abf + NF;                 // 512*512
  ushort* Wt2 = Wt1 + (size_t)D_IN * HC;  // 512*512

  hipMemsetAsync(acc2, 0, zero_bytes, stream);

  // casts (x, W1^T, W2^T) + degree histogram in one launch
  int n4x = (int)(NF / 4);
  int pre_total = n4x + 2 * D_IN * HC + Etot;
  k_pre<<<(pre_total + 255) / 256, 256, 0, stream>>>(x, Abf, W1, W2, Wt1, Wt2, n4x,
                                                     ei, E, Etot, cnt);

  int nwg = (HC / BN) * ((N + BM - 1) / BM);  // 628
  int aggblocks = (N + 3) / 4;                // 4 nodes (waves) per block

  // ---- layer 1: gemm (blocks 1..628) + CSR scan (block 0) in one launch ----
  k_gemm_bf16<NH1, 1><<<nwg + 1, 256, 0, stream>>>(Abf, Wt1, xpbf, as1, ad1, asr1, adt1, N,
                                                   cnt, rowstart, N);
  k_scatter<<<(Etot + 255) / 256, 256, 0, stream>>>(ei, E, Etot, rowstart, cursor, csr_src);
  k_agg<NH1, 1><<<aggblocks, 256, 0, stream>>>(rowstart, csr_src, asr1, adt1, xpbf, Abf,
                                               nullptr, b1, nullptr, nullptr, nullptr, N);

  // ---- layer 2 ----
  k_gemm_bf16<NH2, 0><<<nwg, 256, 0, stream>>>(Abf, Wt2, xpbf, as2, ad2, asr2, adt2, N,
                                               nullptr, nullptr, N);
  k_agg<NH2, 2><<<aggblocks, 256, 0, stream>>>(rowstart, csr_src, asr2, adt2, xpbf, nullptr,
                                               out + 1, b2, y, msk, acc2, N);

  // ---- epilogue: loss ----
  k_final<<<1, 128, 0, stream>>>(acc2, out);
}

// Round 5
// 280.828 us; speedup vs baseline: 1.1761x; 1.0420x over previous
//
#include <hip/hip_runtime.h>
#include <cmath>

#define D_IN 512
#define HC   512   // H1*C1 == H2*C2 == D_IN
#define NH1  8
#define NC1  64
#define NH2  4
#define NC2  128
#define BM 128
#define BN 128
#define BK 64

typedef __attribute__((ext_vector_type(8))) short short8;
typedef __attribute__((ext_vector_type(8))) unsigned short u16x8;
typedef __attribute__((ext_vector_type(4))) float f32x4;

__device__ inline ushort f2bf(float f) {
  unsigned u = __float_as_uint(f);
  return (ushort)((u + 0x7FFFu + ((u >> 16) & 1u)) >> 16);
}
__device__ inline float bf2f(ushort b) { return __uint_as_float(((unsigned)b) << 16); }

// ---------- all input casts + degree histogram in ONE launch ---------------
__global__ void k_pre(const float* __restrict__ x, ushort* __restrict__ Abf,
                      const float* __restrict__ W1, const float* __restrict__ W2,
                      ushort* __restrict__ Wt1, ushort* __restrict__ Wt2, int n4x,
                      const int* __restrict__ ei, int E, int Etot,
                      int* __restrict__ cnt) {
  const int KN = D_IN * HC;
  int i = blockIdx.x * blockDim.x + threadIdx.x;
  if (i < n4x) {
    float4 v = ((const float4*)x)[i];
    ushort4 r = { f2bf(v.x), f2bf(v.y), f2bf(v.z), f2bf(v.w) };
    ((ushort4*)Abf)[i] = r;
  } else if (i < n4x + 2 * KN) {
    int idx = i - n4x;
    const float* W = (idx < KN) ? W1 : W2;
    ushort* Wt = (idx < KN) ? Wt1 : Wt2;
    int j = (idx < KN) ? idx : idx - KN;
    int n = j / D_IN, k = j - n * D_IN;
    Wt[j] = f2bf(W[(size_t)k * HC + n]);
  } else {
    int e = i - n4x - 2 * KN;
    if (e >= Etot) return;
    int d = (e < E) ? ei[E + e] : e - E;
    atomicAdd(&cnt[d], 1);
  }
}

// ---------- bf16 MFMA GEMM (R0 proven form) + fused scan block -------------
// R18 post-mortem of R17: ALL top-5 63us dispatches had LDS=33280 = the SCAN
// instantiation only -> gemm2(swizzle, no scan) never regressed; the fused
// scan block was a ~60us straggler (pass2 `run += cnt[j]` is a loop-carried
// chain through a ~900cy load, x79 iters x2 passes, one block running alone
// at the kernel tail -> occ 10.6%, MfmaUtil 6%). Swizzle exonerated (FETCH
// 18.4->12.9MB as predicted) and kept.
// R18 scan: register-cached two-pass. 256 thr x 20 int4 loads issued once
// (independent -> single latency exposure), wave/block scan of thread sums,
// pass 2 replays prefix FROM REGISTERS (stores only). All loops unrolled
// with static indices (no runtime-indexed reg arrays -> no scratch).
// Serial fallback for N > 20480.
// LDS layout: slot s=(rowgrp)*4+kchunk, addr=(s*16+ln)*8 ushorts; staging
// thread t -> LDS offset t*8 (wave-uniform base + lane*16B as
// global_load_lds requires); ds_read stride-1 across lanes -> conflict-free
// (verified: SQ_LDS_BANK_CONFLICT=0). Do NOT trade occupancy/grid for
// traffic (BN=512 regressed 42->79 us despite 3.5x lower FETCH).
// Att epilogue: plain stores only. H=8 (C=64): one slot per (row,h).
// H=4 (C=128): two partial slots per (row,h): [(row*4+h)*2+sub], sub=col64.
template<int H, int SCAN>
__global__ void k_gemm_bf16(const ushort* __restrict__ A, const ushort* __restrict__ Bt,
                            ushort* __restrict__ Cbf,
                            const float* __restrict__ att_s, const float* __restrict__ att_d,
                            float* __restrict__ asrc, float* __restrict__ adst, int M,
                            const int* __restrict__ cnt, int* __restrict__ rowstart, int Nn) {
  constexpr int C = HC / H;
  __shared__ __align__(16) ushort As[BM * BK];   // 16 KB, two 8KB K-halves
  __shared__ __align__(16) ushort Bs[BN * BK];   // 16 KB
  int t = threadIdx.x;

  if (SCAN && blockIdx.x == 0) {
    // ---- register-cached exclusive prefix scan: cnt[0..Nn) -> rowstart ----
    __shared__ int wsum[4];
    constexpr int MAXT4 = 20;                 // covers Nn <= 256*20*4 = 20480
    int T4 = (Nn + 1023) >> 10;               // int4s per thread
    int lane = t & 63, w = t >> 6;
    if (T4 <= MAXT4) {
      const int4* c4 = (const int4*)cnt;      // 16B-aligned (ws layout)
      int nb4 = (Nn + 3) >> 2;
      int4 v4[MAXT4];
#pragma unroll
      for (int i = 0; i < MAXT4; ++i) {
        int j4 = t * T4 + i;
        int4 z = {0, 0, 0, 0};
        v4[i] = (i < T4 && j4 < nb4) ? c4[j4] : z;   // tail int4 reads zeroed cursor
      }
      int sum = 0;
#pragma unroll
      for (int i = 0; i < MAXT4; ++i) sum += v4[i].x + v4[i].y + v4[i].z + v4[i].w;
      int v = sum;
#pragma unroll
      for (int off = 1; off < 64; off <<= 1) {
        int u = __shfl_up(v, off);
        if (lane >= off) v += u;
      }
      if (lane == 63) wsum[w] = v;
      __syncthreads();
      int wp = 0;
      for (int i = 0; i < 4; ++i) if (i < w) wp += wsum[i];
      int run = wp + v - sum;                 // exclusive prefix for this thread
#pragma unroll
      for (int i = 0; i < MAXT4; ++i) {
        int jb = (t * T4 + i) * 4;
        if (jb + 0 < Nn) rowstart[jb + 0] = run;  run += v4[i].x;
        if (jb + 1 < Nn) rowstart[jb + 1] = run;  run += v4[i].y;
        if (jb + 2 < Nn) rowstart[jb + 2] = run;  run += v4[i].z;
        if (jb + 3 < Nn) rowstart[jb + 3] = run;  run += v4[i].w;
      }
      if (t == 255) rowstart[Nn] = run;       // pads are zero -> run == total
    } else {
      // serial fallback (large N)
      int T = (Nn + 255) / 256;
      int base = t * T;
      int sum = 0;
      for (int i = 0; i < T; ++i) { int j = base + i; if (j < Nn) sum += cnt[j]; }
      int v = sum;
#pragma unroll
      for (int off = 1; off < 64; off <<= 1) {
        int u = __shfl_up(v, off);
        if (lane >= off) v += u;
      }
      if (lane == 63) wsum[w] = v;
      __syncthreads();
      int wp = 0;
      for (int i = 0; i < 4; ++i) if (i < w) wp += wsum[i];
      int run = wp + v - sum;
      for (int i = 0; i < T; ++i) {
        int j = base + i;
        if (j < Nn) { rowstart[j] = run; run += cnt[j]; }
      }
      if (t == 255) rowstart[Nn] = run;
    }
    return;
  }

  int lin = blockIdx.x - (SCAN ? 1 : 0);
  int nwg = gridDim.x - (SCAN ? 1 : 0);     // 628
  // chunked bijective XCD swizzle: round-robin-assigned blocks -> contiguous
  // wg chunk per XCD (consecutive wg share the A panel). FETCH 18.4->12.9MB.
  int q = nwg >> 3, r = nwg & 7;
  int xcd = lin & 7, pos = lin >> 3;
  int wg = (xcd < r ? xcd * (q + 1) : r * (q + 1) + (xcd - r) * q) + pos;
  int m0 = (wg >> 2) * BM;                  // 4 n-tiles per m-panel
  int n0 = (wg & 3) * BN;

  int wave = t >> 6, lane = t & 63;
  int ln = lane & 15, qd = lane >> 4;
  int wm = (wave >> 1) * 64, wn = (wave & 1) * 64;

  f32x4 acc[4][4] = {};

  int g = t >> 6, ct = (t >> 4) & 3, lt = t & 15;
  int rA0 = m0 + g * 16 + lt;      if (rA0 > M - 1) rA0 = M - 1;
  int rA1 = m0 + 64 + g * 16 + lt; if (rA1 > M - 1) rA1 = M - 1;
  const ushort* gA0 = A + (size_t)rA0 * D_IN + ct * 8;
  const ushort* gA1 = A + (size_t)rA1 * D_IN + ct * 8;
  const ushort* gB0 = Bt + (size_t)(n0 + g * 16 + lt) * D_IN + ct * 8;
  const ushort* gB1 = Bt + (size_t)(n0 + 64 + g * 16 + lt) * D_IN + ct * 8;

  for (int k0 = 0; k0 < D_IN; k0 += BK) {
    __syncthreads();
#pragma unroll
    for (int h = 0; h < 2; ++h) {
      int ko = k0 + h * 32;
      int lo = h * 4096;
      __builtin_amdgcn_global_load_lds(
          (const __attribute__((address_space(1))) void*)(gA0 + ko),
          (__attribute__((address_space(3))) void*)(As + lo + t * 8), 16, 0, 0);
      __builtin_amdgcn_global_load_lds(
          (const __attribute__((address_space(1))) void*)(gA1 + ko),
          (__attribute__((address_space(3))) void*)(As + lo + 2048 + t * 8), 16, 0, 0);
      __builtin_amdgcn_global_load_lds(
          (const __attribute__((address_space(1))) void*)(gB0 + ko),
          (__attribute__((address_space(3))) void*)(Bs + lo + t * 8), 16, 0, 0);
      __builtin_amdgcn_global_load_lds(
          (const __attribute__((address_space(1))) void*)(gB1 + ko),
          (__attribute__((address_space(3))) void*)(Bs + lo + 2048 + t * 8), 16, 0, 0);
    }
    __syncthreads();
#pragma unroll
    for (int h = 0; h < 2; ++h) {
      int lo = h * 4096;
      short8 a[4], bb[4];
#pragma unroll
      for (int i = 0; i < 4; ++i)
        a[i] = *(const short8*)&As[lo + (((wave >> 1) * 4 + i) * 4 + qd) * 128 + ln * 8];
#pragma unroll
      for (int j = 0; j < 4; ++j)
        bb[j] = *(const short8*)&Bs[lo + (((wave & 1) * 4 + j) * 4 + qd) * 128 + ln * 8];
#pragma unroll
      for (int i = 0; i < 4; ++i)
#pragma unroll
        for (int j = 0; j < 4; ++j)
          acc[i][j] = __builtin_amdgcn_mfma_f32_16x16x32_bf16(a[i], bb[j], acc[i][j], 0, 0, 0);
    }
  }

  // ---- C store (C/D layout: col = ln, row = qd*4 + reg) ----
#pragma unroll
  for (int i = 0; i < 4; ++i) {
#pragma unroll
    for (int reg = 0; reg < 4; ++reg) {
      int row = m0 + wm + i * 16 + qd * 4 + reg;
      if (row >= M) continue;
#pragma unroll
      for (int j = 0; j < 4; ++j)
        Cbf[(size_t)row * HC + n0 + wn + j * 16 + ln] = f2bf(acc[i][j][reg]);
    }
  }

  // ---- fused attention scores (plain stores only) ----
  int colbase = n0 + wn;         // multiple of 64
  int h = colbase / C;
  float sa[4], da[4];
#pragma unroll
  for (int j = 0; j < 4; ++j) {
    int c = (colbase % C) + j * 16 + ln;
    sa[j] = att_s[h * C + c];
    da[j] = att_d[h * C + c];
  }
#pragma unroll
  for (int i = 0; i < 4; ++i) {
#pragma unroll
    for (int reg = 0; reg < 4; ++reg) {
      float ps = acc[i][0][reg] * sa[0] + acc[i][1][reg] * sa[1]
               + acc[i][2][reg] * sa[2] + acc[i][3][reg] * sa[3];
      float pd = acc[i][0][reg] * da[0] + acc[i][1][reg] * da[1]
               + acc[i][2][reg] * da[2] + acc[i][3][reg] * da[3];
#pragma unroll
      for (int o = 1; o < 16; o <<= 1) { ps += __shfl_xor(ps, o); pd += __shfl_xor(pd, o); }
      int row = m0 + wm + i * 16 + qd * 4 + reg;
      if (ln == 0 && row < M) {
        if (C == 64) {
          asrc[row * H + h] = ps; adst[row * H + h] = pd;
        } else {
          int sub = (colbase >> 6) & 1;
          asrc[(row * H + h) * 2 + sub] = ps;
          adst[(row * H + h) * 2 + sub] = pd;
        }
      }
    }
  }
}

__global__ void k_scatter(const int* __restrict__ ei, int E, int Etot,
                          const int* __restrict__ rowstart, int* __restrict__ cursor,
                          int* __restrict__ csr_src) {
  int e = blockIdx.x * blockDim.x + threadIdx.x;
  if (e >= Etot) return;
  int s = (e < E) ? ei[e] : e - E;
  int d = (e < E) ? ei[E + e] : e - E;
  int pos = atomicAdd(&cursor[d], 1);
  csr_src[rowstart[d] + pos] = s;
}

// -------- gather aggregation, ONE WAVE PER NODE, 4-way unroll --------------
// MODE 1 (H=8): scores at [x*H+h]; hout = bf16(elu(sum/den + b)).
// MODE 2 (H=4): scores are 2 partials at [(x*H+h)*2+{0,1}];
//   head-mean via shfl_xor(16,32) fold; fused CE via 16-lane butterflies.
template<int H, int MODE>
__global__ void k_agg(const int* __restrict__ rowstart, const int* __restrict__ csr_src,
                      const float* __restrict__ asrc, const float* __restrict__ adst,
                      const ushort* __restrict__ xp, ushort* __restrict__ hout,
                      float* __restrict__ out2, const float* __restrict__ bias,
                      const int* __restrict__ y, const int* __restrict__ msk,
                      float* __restrict__ acc2, int N) {
  int wv = threadIdx.x >> 6, lane = threadIdx.x & 63;
  int n = blockIdx.x * 4 + wv;
  if (n >= N) return;                         // wave-uniform
  int h = (MODE == 1) ? (lane >> 3) : (lane >> 4);   // 8 chans/lane
  int beg = rowstart[n], end = rowstart[n + 1];

  float adn;
  if (MODE == 1) adn = adst[n * H + h];
  else { float2 t2 = ((const float2*)adst)[n * H + h]; adn = t2.x + t2.y; }

  float acc[8] = {};
  float wsum = 0.f;

#define SCR(s_)  ((MODE == 1) ? asrc[(s_) * H + h] \
                   : (((const float2*)asrc)[(s_) * H + h].x + \
                      ((const float2*)asrc)[(s_) * H + h].y))
#define EDGE(w_, a_)  do {                                   \
    float ww = (w_);                                         \
    _Pragma("unroll") for (int k = 0; k < 8; ++k)            \
      acc[k] += ww * bf2f((a_)[k]);                          \
    wsum += ww; } while (0)
#define LRELU(v_) ((v_) > 0.f ? (v_) : 0.2f * (v_))

  for (int c0 = beg; c0 < end; c0 += 64) {
    int len = end - c0; if (len > 64) len = 64;
    int ev = (lane < len) ? csr_src[c0 + lane] : 0;
    int j = 0;
    for (; j + 3 < len; j += 4) {
      int s0 = __shfl(ev, j), s1 = __shfl(ev, j + 1);
      int s2 = __shfl(ev, j + 2), s3 = __shfl(ev, j + 3);
      float v0 = SCR(s0) + adn, v1 = SCR(s1) + adn;
      float v2 = SCR(s2) + adn, v3 = SCR(s3) + adn;
      u16x8 a0 = ((const u16x8*)xp)[(size_t)s0 * 64 + lane];
      u16x8 a1 = ((const u16x8*)xp)[(size_t)s1 * 64 + lane];
      u16x8 a2 = ((const u16x8*)xp)[(size_t)s2 * 64 + lane];
      u16x8 a3 = ((const u16x8*)xp)[(size_t)s3 * 64 + lane];
      EDGE(__expf(LRELU(v0)), a0);
      EDGE(__expf(LRELU(v1)), a1);
      EDGE(__expf(LRELU(v2)), a2);
      EDGE(__expf(LRELU(v3)), a3);
    }
    for (; j + 1 < len; j += 2) {
      int s0 = __shfl(ev, j), s1 = __shfl(ev, j + 1);
      float v0 = SCR(s0) + adn, v1 = SCR(s1) + adn;
      u16x8 a0 = ((const u16x8*)xp)[(size_t)s0 * 64 + lane];
      u16x8 a1 = ((const u16x8*)xp)[(size_t)s1 * 64 + lane];
      EDGE(__expf(LRELU(v0)), a0);
      EDGE(__expf(LRELU(v1)), a1);
    }
    if (j < len) {
      int s0 = __shfl(ev, j);
      float v0 = SCR(s0) + adn;
      u16x8 a0 = ((const u16x8*)xp)[(size_t)s0 * 64 + lane];
      EDGE(__expf(LRELU(v0)), a0);
    }
  }
#undef SCR
#undef EDGE
#undef LRELU

  float rdn = 1.0f / (wsum + 1e-16f);
#pragma unroll
  for (int k = 0; k < 8; ++k) acc[k] *= rdn;

  if (MODE == 1) {
    int c = lane * 8;
    u16x8 rr;
#pragma unroll
    for (int k = 0; k < 8; ++k) {
      float v = acc[k] + bias[c + k];
      v = (v > 0.f) ? v : expm1f(v);
      rr[k] = f2bf(v);
    }
    ((u16x8*)hout)[(size_t)n * 64 + lane] = rr;
  } else {
    // head-mean: channel c'=(lane&15)*8+k lives on lanes {l, l^16, l^32, l^48}
#pragma unroll
    for (int k = 0; k < 8; ++k) {
      float v = acc[k];
      v += __shfl_xor(v, 16);
      v += __shfl_xor(v, 32);
      acc[k] = v * 0.25f + bias[(lane & 15) * 8 + k];
    }
    if (lane < 16) {       // scalar stores: out2 = out+1 is only 4B-aligned
      int cb = lane * 8;
#pragma unroll
      for (int k = 0; k < 8; ++k) out2[(size_t)n * NC2 + cb + k] = acc[k];
    }
    // fused CE: lanes 0..15 hold the 128 logits (copies in upper 48 lanes)
    float mx = acc[0];
#pragma unroll
    for (int k = 1; k < 8; ++k) mx = fmaxf(mx, acc[k]);
#pragma unroll
    for (int o = 1; o < 16; o <<= 1) mx = fmaxf(mx, __shfl_xor(mx, o));
    float e = 0.f;
#pragma unroll
    for (int k = 0; k < 8; ++k) e += __expf(acc[k] - mx);
#pragma unroll
    for (int o = 1; o < 16; o <<= 1) e += __shfl_xor(e, o);
    int yv = y[n];
    float sel = acc[0];
#pragma unroll
    for (int k = 1; k < 8; ++k) sel = ((yv & 7) == k) ? acc[k] : sel;
    float vy = __shfl(sel, yv >> 3);
    if (lane == 0 && msk[n] != 0) {
      float ce = mx + logf(e) - vy;
      int slot = n & 127;
      atomicAdd(&acc2[slot], ce);
      atomicAdd(&acc2[128 + slot], 1.0f);
    }
  }
}

__global__ void k_final(const float* __restrict__ acc2, float* __restrict__ out0) {
  int tid = threadIdx.x;   // 128 threads
  float ce = acc2[tid], ct = acc2[128 + tid];
#pragma unroll
  for (int o = 32; o > 0; o >>= 1) { ce += __shfl_xor(ce, o); ct += __shfl_xor(ct, o); }
  __shared__ float s[4];
  if ((tid & 63) == 0) { s[(tid >> 6) * 2] = ce; s[(tid >> 6) * 2 + 1] = ct; }
  __syncthreads();
  if (tid == 0) out0[0] = (s[0] + s[2]) / (s[1] + s[3]);
}

extern "C" void kernel_launch(void* const* d_in, const int* in_sizes, int n_in,
                              void* d_out, int out_size, void* d_ws, size_t ws_size,
                              hipStream_t stream) {
  const float* x   = (const float*)d_in[0];
  const int*   ei  = (const int*)d_in[1];
  const int*   y   = (const int*)d_in[2];
  const int*   msk = (const int*)d_in[3];
  const float* W1  = (const float*)d_in[4];
  const float* as1 = (const float*)d_in[5];
  const float* ad1 = (const float*)d_in[6];
  const float* b1  = (const float*)d_in[7];
  const float* W2  = (const float*)d_in[8];
  const float* as2 = (const float*)d_in[9];
  const float* ad2 = (const float*)d_in[10];
  const float* b2  = (const float*)d_in[11];
  float* out = (float*)d_out;

  int N = in_sizes[0] / D_IN;   // 20000
  int E = in_sizes[1] / 2;      // 100000
  int Etot = E + N;             // 120000 (self-loops appended)

  float* ws = (float*)d_ws;
  size_t NF = (size_t)N * HC;
  float* asr1 = ws;                       // N*8  (plain-written in GEMM1)
  float* adt1 = asr1 + (size_t)N * NH1;   // N*8
  float* asr2 = adt1 + (size_t)N * NH1;   // N*8  (partials, plain-written GEMM2)
  float* adt2 = asr2 + (size_t)N * 2 * NH2; // N*8
  // ---- zero-init region: acc2, cnt, cursor (contiguous) ----
  float* acc2 = adt2 + (size_t)N * 2 * NH2; // 256
  int*   cnt    = (int*)(acc2 + 256);     // N
  int*   cursor = cnt + N;                // N (zeroed; also pads scan's int4 tail)
  size_t zero_bytes = (256 + 2 * (size_t)N) * sizeof(float);
  // ---- fully-written region ----
  int*   rowstart = cursor + N;           // N+1
  int*   csr_src  = rowstart + N + 1;     // Etot
  ushort* xpbf = (ushort*)((((uintptr_t)(csr_src + Etot)) + 15) & ~(uintptr_t)15);
  ushort* Abf = xpbf + NF;                // N*512
  ushort* Wt1 = Abf + NF;                 // 512*512
  ushort* Wt2 = Wt1 + (size_t)D_IN * HC;  // 512*512

  hipMemsetAsync(acc2, 0, zero_bytes, stream);

  // casts (x, W1^T, W2^T) + degree histogram in one launch
  int n4x = (int)(NF / 4);
  int pre_total = n4x + 2 * D_IN * HC + Etot;
  k_pre<<<(pre_total + 255) / 256, 256, 0, stream>>>(x, Abf, W1, W2, Wt1, Wt2, n4x,
                                                     ei, E, Etot, cnt);

  int nwg = (HC / BN) * ((N + BM - 1) / BM);  // 628
  int aggblocks = (N + 3) / 4;                // 4 nodes (waves) per block

  // ---- layer 1: gemm (blocks 1..628) + CSR scan (block 0) in one launch ----
  k_gemm_bf16<NH1, 1><<<nwg + 1, 256, 0, stream>>>(Abf, Wt1, xpbf, as1, ad1, asr1, adt1, N,
                                                   cnt, rowstart, N);
  k_scatter<<<(Etot + 255) / 256, 256, 0, stream>>>(ei, E, Etot, rowstart, cursor, csr_src);
  k_agg<NH1, 1><<<aggblocks, 256, 0, stream>>>(rowstart, csr_src, asr1, adt1, xpbf, Abf,
                                               nullptr, b1, nullptr, nullptr, nullptr, N);

  // ---- layer 2 ----
  k_gemm_bf16<NH2, 0><<<nwg, 256, 0, stream>>>(Abf, Wt2, xpbf, as2, ad2, asr2, adt2, N,
                                               nullptr, nullptr, N);
  k_agg<NH2, 2><<<aggblocks, 256, 0, stream>>>(rowstart, csr_src, asr2, adt2, xpbf, nullptr,
                                               out + 1, b2, y, msk, acc2, N);

  // ---- epilogue: loss ----
  k_final<<<1, 128, 0, stream>>>(acc2, out);
}

// Round 6
// 266.037 us; speedup vs baseline: 1.2415x; 1.0556x over previous
//
#include <hip/hip_runtime.h>
#include <cmath>

#define D_IN 512
#define HC   512   // H1*C1 == H2*C2 == D_IN
#define NH1  8
#define NC1  64
#define NH2  4
#define NC2  128
#define BM 128
#define BN 128
#define BK 64

typedef __attribute__((ext_vector_type(8))) short short8;
typedef __attribute__((ext_vector_type(8))) unsigned short u16x8;
typedef __attribute__((ext_vector_type(8))) unsigned short ushort8;
typedef __attribute__((ext_vector_type(4))) float f32x4;

__device__ inline ushort f2bf(float f) {
  unsigned u = __float_as_uint(f);
  return (ushort)((u + 0x7FFFu + ((u >> 16) & 1u)) >> 16);
}
__device__ inline float bf2f(ushort b) { return __uint_as_float(((unsigned)b) << 16); }

// ---------- casts + W-tile-transpose + degree histogram in ONE launch ------
// R19: W transpose was per-element (read stride 2KB -> 8x line overfetch on
// 2MB). Now 64x64 LDS tile transpose: 128 tile-blocks, [64][65] pad (2-way
// bank conflict = free), coalesced float4 in / ushort8 out.
// Block regions: [0,nxb) x-cast | [nxb,nxb+128) W tiles | rest: histogram.
__global__ void k_pre(const float* __restrict__ x, ushort* __restrict__ Abf,
                      const float* __restrict__ W1, const float* __restrict__ W2,
                      ushort* __restrict__ Wt1, ushort* __restrict__ Wt2, int n4x,
                      const int* __restrict__ ei, int E, int Etot,
                      int* __restrict__ cnt) {
  __shared__ float tl[64][65];
  int t = threadIdx.x;
  int bx = blockIdx.x;
  int nxb = (n4x + 255) >> 8;
  if (bx < nxb) {
    int i = bx * 256 + t;
    if (i < n4x) {
      float4 v = ((const float4*)x)[i];
      ushort4 r = { f2bf(v.x), f2bf(v.y), f2bf(v.z), f2bf(v.w) };
      ((ushort4*)Abf)[i] = r;
    }
  } else if (bx < nxb + 128) {
    int b = bx - nxb;
    int w = b >> 6, tile = b & 63;
    int k0 = (tile >> 3) * 64, n0 = (tile & 7) * 64;
    const float* W = w ? W2 : W1;
    ushort* Wt = w ? Wt2 : Wt1;
    int r = t >> 2, q = t & 3;
    const float4* src = (const float4*)(W + (size_t)(k0 + r) * HC + n0 + q * 16);
#pragma unroll
    for (int j = 0; j < 4; ++j) {
      float4 v = src[j];
      tl[r][q * 16 + 4 * j + 0] = v.x;
      tl[r][q * 16 + 4 * j + 1] = v.y;
      tl[r][q * 16 + 4 * j + 2] = v.z;
      tl[r][q * 16 + 4 * j + 3] = v.w;
    }
    __syncthreads();
    // Wt[n0+r][k0+q*16 .. +16) = W[k][n0+r] = tl[k-k0][r]
    ushort8* dst = (ushort8*)(Wt + (size_t)(n0 + r) * D_IN + k0 + q * 16);
#pragma unroll
    for (int j = 0; j < 2; ++j) {
      ushort8 o;
#pragma unroll
      for (int c = 0; c < 8; ++c) o[c] = f2bf(tl[q * 16 + 8 * j + c][r]);
      dst[j] = o;
    }
  } else {
    int e = (bx - nxb - 128) * 256 + t;
    if (e >= Etot) return;
    int d = (e < E) ? ei[E + e] : e - E;
    atomicAdd(&cnt[d], 1);
  }
}

// ---------- bf16 MFMA GEMM (R0 proven form) + fused scan block -------------
// R19 scan (3rd design): R5's v4[20] register cache needed 80 VGPR, kernel
// allocates 64 -> scratch spill + per-element load->cndmask waits; scan
// block still straggled ~10us past the gemm makespan (gemm1 51.5 vs gemm2
// <42). Now: two passes over cnt (2nd L2-hot), chunk sums in LDS REUSING
// As/Bs (no LDS growth), coalesced int4 loads (g=i*256+t), thread-contiguous
// chunk scan (shfl_up + 4-wave combine), coalesced rowstart stores. ~20
// VGPR, no spills, no serial load chains. If gemm1 stays ~51us the SCAN
// instantiation codegen is the drag -> revert to separate launch.
// Swizzle: chunked bijective XCD (FETCH 18.4->12.9MB, kept).
// LDS layout (gemm): slot s=(rowgrp)*4+kchunk, addr=(s*16+ln)*8 ushorts;
// staging thread t -> LDS offset t*8; ds_read stride-1 -> conflict-free.
// Do NOT trade occupancy/grid for traffic (BN=512 regressed 42->79).
// Att epilogue: plain stores only. H=8: one slot/(row,h). H=4: two partial
// slots [(row*4+h)*2+sub], sub=col64-idx.
template<int H, int SCAN>
__global__ void k_gemm_bf16(const ushort* __restrict__ A, const ushort* __restrict__ Bt,
                            ushort* __restrict__ Cbf,
                            const float* __restrict__ att_s, const float* __restrict__ att_d,
                            float* __restrict__ asrc, float* __restrict__ adst, int M,
                            const int* __restrict__ cnt, int* __restrict__ rowstart, int Nn) {
  constexpr int C = HC / H;
  __shared__ __align__(16) ushort As[BM * BK];   // 16 KB, two 8KB K-halves
  __shared__ __align__(16) ushort Bs[BN * BK];   // 16 KB
  int t = threadIdx.x;

  if (SCAN && blockIdx.x == 0) {
    // ---- two-pass LDS-chunked exclusive scan: cnt[0..Nn) -> rowstart ----
    int* sA = (int*)As;                       // 4096 ints
    int* sB = (int*)Bs;                       // 4096 ints (chunks 4096..5119 + wsum)
    int lane = t & 63, w = t >> 6;
    const int4* c4 = (const int4*)cnt;        // 16B-aligned (ws layout)
    int nb4 = (Nn + 3) >> 2;
    int T4 = (nb4 + 255) >> 8;                // chunks per thread
    if (T4 <= 20) {                           // Nn <= 20480
      // pass 1: coalesced loads, chunk sums -> LDS
      for (int i = 0; i < T4; ++i) {
        int g = i * 256 + t;
        int s = 0;
        if (g < nb4) { int4 v = c4[g]; s = v.x + v.y + v.z + v.w; }
        (g < 4096 ? sA[g] : sB[g - 4096]) = s;
      }
      __syncthreads();
      // thread-contiguous scan over chunk sums
      int base = t * T4;
      int S = 0;
      for (int i = 0; i < T4; ++i) {
        int g = base + i;
        if (g < nb4) S += (g < 4096 ? sA[g] : sB[g - 4096]);
      }
      int v = S;
#pragma unroll
      for (int off = 1; off < 64; off <<= 1) {
        int u = __shfl_up(v, off);
        if (lane >= off) v += u;
      }
      if (lane == 63) sB[3000 + w] = v;
      __syncthreads();
      int wp = 0;
#pragma unroll
      for (int i = 0; i < 4; ++i) if (i < w) wp += sB[3000 + i];
      int run = wp + v - S;                   // exclusive prefix for this thread
      for (int i = 0; i < T4; ++i) {          // own cells only -> no barrier needed
        int g = base + i;
        if (g < nb4) {
          int c = (g < 4096 ? sA[g] : sB[g - 4096]);
          (g < 4096 ? sA[g] : sB[g - 4096]) = run;
          run += c;
        }
      }
      __syncthreads();
      // pass 2: reload (L2-hot), write rowstart coalesced
      for (int i = 0; i < T4; ++i) {
        int g = i * 256 + t;
        if (g < nb4) {
          int4 v = c4[g];
          int p = (g < 4096 ? sA[g] : sB[g - 4096]);
          int jb = g * 4;
          if (jb + 0 < Nn) rowstart[jb + 0] = p;  p += v.x;
          if (jb + 1 < Nn) rowstart[jb + 1] = p;  p += v.y;
          if (jb + 2 < Nn) rowstart[jb + 2] = p;  p += v.z;
          if (jb + 3 < Nn) rowstart[jb + 3] = p;  p += v.w;
          if (jb + 4 >= Nn) rowstart[Nn] = p;     // pads read zeroed cursor
        }
      }
    } else {
      // serial fallback (large N)
      int T = (Nn + 255) / 256;
      int base = t * T;
      int sum = 0;
      for (int i = 0; i < T; ++i) { int j = base + i; if (j < Nn) sum += cnt[j]; }
      int v = sum;
#pragma unroll
      for (int off = 1; off < 64; off <<= 1) {
        int u = __shfl_up(v, off);
        if (lane >= off) v += u;
      }
      if (lane == 63) sB[3000 + w] = v;
      __syncthreads();
      int wp = 0;
#pragma unroll
      for (int i = 0; i < 4; ++i) if (i < w) wp += sB[3000 + i];
      int run = wp + v - sum;
      for (int i = 0; i < T; ++i) {
        int j = base + i;
        if (j < Nn) { rowstart[j] = run; run += cnt[j]; }
      }
      if (t == 255) rowstart[Nn] = run;
    }
    return;
  }

  int lin = blockIdx.x - (SCAN ? 1 : 0);
  int nwg = gridDim.x - (SCAN ? 1 : 0);     // 628
  // chunked bijective XCD swizzle: round-robin-assigned blocks -> contiguous
  // wg chunk per XCD (consecutive wg share the A panel). FETCH 18.4->12.9MB.
  int q = nwg >> 3, r = nwg & 7;
  int xcd = lin & 7, pos = lin >> 3;
  int wg = (xcd < r ? xcd * (q + 1) : r * (q + 1) + (xcd - r) * q) + pos;
  int m0 = (wg >> 2) * BM;                  // 4 n-tiles per m-panel
  int n0 = (wg & 3) * BN;

  int wave = t >> 6, lane = t & 63;
  int ln = lane & 15, qd = lane >> 4;
  int wm = (wave >> 1) * 64, wn = (wave & 1) * 64;

  f32x4 acc[4][4] = {};

  int g = t >> 6, ct = (t >> 4) & 3, lt = t & 15;
  int rA0 = m0 + g * 16 + lt;      if (rA0 > M - 1) rA0 = M - 1;
  int rA1 = m0 + 64 + g * 16 + lt; if (rA1 > M - 1) rA1 = M - 1;
  const ushort* gA0 = A + (size_t)rA0 * D_IN + ct * 8;
  const ushort* gA1 = A + (size_t)rA1 * D_IN + ct * 8;
  const ushort* gB0 = Bt + (size_t)(n0 + g * 16 + lt) * D_IN + ct * 8;
  const ushort* gB1 = Bt + (size_t)(n0 + 64 + g * 16 + lt) * D_IN + ct * 8;

  for (int k0 = 0; k0 < D_IN; k0 += BK) {
    __syncthreads();
#pragma unroll
    for (int h = 0; h < 2; ++h) {
      int ko = k0 + h * 32;
      int lo = h * 4096;
      __builtin_amdgcn_global_load_lds(
          (const __attribute__((address_space(1))) void*)(gA0 + ko),
          (__attribute__((address_space(3))) void*)(As + lo + t * 8), 16, 0, 0);
      __builtin_amdgcn_global_load_lds(
          (const __attribute__((address_space(1))) void*)(gA1 + ko),
          (__attribute__((address_space(3))) void*)(As + lo + 2048 + t * 8), 16, 0, 0);
      __builtin_amdgcn_global_load_lds(
          (const __attribute__((address_space(1))) void*)(gB0 + ko),
          (__attribute__((address_space(3))) void*)(Bs + lo + t * 8), 16, 0, 0);
      __builtin_amdgcn_global_load_lds(
          (const __attribute__((address_space(1))) void*)(gB1 + ko),
          (__attribute__((address_space(3))) void*)(Bs + lo + 2048 + t * 8), 16, 0, 0);
    }
    __syncthreads();
#pragma unroll
    for (int h = 0; h < 2; ++h) {
      int lo = h * 4096;
      short8 a[4], bb[4];
#pragma unroll
      for (int i = 0; i < 4; ++i)
        a[i] = *(const short8*)&As[lo + (((wave >> 1) * 4 + i) * 4 + qd) * 128 + ln * 8];
#pragma unroll
      for (int j = 0; j < 4; ++j)
        bb[j] = *(const short8*)&Bs[lo + (((wave & 1) * 4 + j) * 4 + qd) * 128 + ln * 8];
#pragma unroll
      for (int i = 0; i < 4; ++i)
#pragma unroll
        for (int j = 0; j < 4; ++j)
          acc[i][j] = __builtin_amdgcn_mfma_f32_16x16x32_bf16(a[i], bb[j], acc[i][j], 0, 0, 0);
    }
  }

  // ---- C store (C/D layout: col = ln, row = qd*4 + reg) ----
#pragma unroll
  for (int i = 0; i < 4; ++i) {
#pragma unroll
    for (int reg = 0; reg < 4; ++reg) {
      int row = m0 + wm + i * 16 + qd * 4 + reg;
      if (row >= M) continue;
#pragma unroll
      for (int j = 0; j < 4; ++j)
        Cbf[(size_t)row * HC + n0 + wn + j * 16 + ln] = f2bf(acc[i][j][reg]);
    }
  }

  // ---- fused attention scores (plain stores only) ----
  int colbase = n0 + wn;         // multiple of 64
  int h = colbase / C;
  float sa[4], da[4];
#pragma unroll
  for (int j = 0; j < 4; ++j) {
    int c = (colbase % C) + j * 16 + ln;
    sa[j] = att_s[h * C + c];
    da[j] = att_d[h * C + c];
  }
#pragma unroll
  for (int i = 0; i < 4; ++i) {
#pragma unroll
    for (int reg = 0; reg < 4; ++reg) {
      float ps = acc[i][0][reg] * sa[0] + acc[i][1][reg] * sa[1]
               + acc[i][2][reg] * sa[2] + acc[i][3][reg] * sa[3];
      float pd = acc[i][0][reg] * da[0] + acc[i][1][reg] * da[1]
               + acc[i][2][reg] * da[2] + acc[i][3][reg] * da[3];
#pragma unroll
      for (int o = 1; o < 16; o <<= 1) { ps += __shfl_xor(ps, o); pd += __shfl_xor(pd, o); }
      int row = m0 + wm + i * 16 + qd * 4 + reg;
      if (ln == 0 && row < M) {
        if (C == 64) {
          asrc[row * H + h] = ps; adst[row * H + h] = pd;
        } else {
          int sub = (colbase >> 6) & 1;
          asrc[(row * H + h) * 2 + sub] = ps;
          adst[(row * H + h) * 2 + sub] = pd;
        }
      }
    }
  }
}

__global__ void k_scatter(const int* __restrict__ ei, int E, int Etot,
                          const int* __restrict__ rowstart, int* __restrict__ cursor,
                          int* __restrict__ csr_src) {
  int e = blockIdx.x * blockDim.x + threadIdx.x;
  if (e >= Etot) return;
  int s = (e < E) ? ei[e] : e - E;
  int d = (e < E) ? ei[E + e] : e - E;
  int pos = atomicAdd(&cursor[d], 1);
  csr_src[rowstart[d] + pos] = s;
}

// -------- gather aggregation, ONE WAVE PER NODE, 4-way unroll --------------
// MODE 1 (H=8): scores at [x*H+h]; hout = bf16(elu(sum/den + b)).
// MODE 2 (H=4): scores are 2 partials at [(x*H+h)*2+{0,1}];
//   head-mean via shfl_xor(16,32) fold; fused CE via 16-lane butterflies.
template<int H, int MODE>
__global__ void k_agg(const int* __restrict__ rowstart, const int* __restrict__ csr_src,
                      const float* __restrict__ asrc, const float* __restrict__ adst,
                      const ushort* __restrict__ xp, ushort* __restrict__ hout,
                      float* __restrict__ out2, const float* __restrict__ bias,
                      const int* __restrict__ y, const int* __restrict__ msk,
                      float* __restrict__ acc2, int N) {
  int wv = threadIdx.x >> 6, lane = threadIdx.x & 63;
  int n = blockIdx.x * 4 + wv;
  if (n >= N) return;                         // wave-uniform
  int h = (MODE == 1) ? (lane >> 3) : (lane >> 4);   // 8 chans/lane
  int beg = rowstart[n], end = rowstart[n + 1];

  float adn;
  if (MODE == 1) adn = adst[n * H + h];
  else { float2 t2 = ((const float2*)adst)[n * H + h]; adn = t2.x + t2.y; }

  float acc[8] = {};
  float wsum = 0.f;

#define SCR(s_)  ((MODE == 1) ? asrc[(s_) * H + h] \
                   : (((const float2*)asrc)[(s_) * H + h].x + \
                      ((const float2*)asrc)[(s_) * H + h].y))
#define EDGE(w_, a_)  do {                                   \
    float ww = (w_);                                         \
    _Pragma("unroll") for (int k = 0; k < 8; ++k)            \
      acc[k] += ww * bf2f((a_)[k]);                          \
    wsum += ww; } while (0)
#define LRELU(v_) ((v_) > 0.f ? (v_) : 0.2f * (v_))

  for (int c0 = beg; c0 < end; c0 += 64) {
    int len = end - c0; if (len > 64) len = 64;
    int ev = (lane < len) ? csr_src[c0 + lane] : 0;
    int j = 0;
    for (; j + 3 < len; j += 4) {
      int s0 = __shfl(ev, j), s1 = __shfl(ev, j + 1);
      int s2 = __shfl(ev, j + 2), s3 = __shfl(ev, j + 3);
      float v0 = SCR(s0) + adn, v1 = SCR(s1) + adn;
      float v2 = SCR(s2) + adn, v3 = SCR(s3) + adn;
      u16x8 a0 = ((const u16x8*)xp)[(size_t)s0 * 64 + lane];
      u16x8 a1 = ((const u16x8*)xp)[(size_t)s1 * 64 + lane];
      u16x8 a2 = ((const u16x8*)xp)[(size_t)s2 * 64 + lane];
      u16x8 a3 = ((const u16x8*)xp)[(size_t)s3 * 64 + lane];
      EDGE(__expf(LRELU(v0)), a0);
      EDGE(__expf(LRELU(v1)), a1);
      EDGE(__expf(LRELU(v2)), a2);
      EDGE(__expf(LRELU(v3)), a3);
    }
    for (; j + 1 < len; j += 2) {
      int s0 = __shfl(ev, j), s1 = __shfl(ev, j + 1);
      float v0 = SCR(s0) + adn, v1 = SCR(s1) + adn;
      u16x8 a0 = ((const u16x8*)xp)[(size_t)s0 * 64 + lane];
      u16x8 a1 = ((const u16x8*)xp)[(size_t)s1 * 64 + lane];
      EDGE(__expf(LRELU(v0)), a0);
      EDGE(__expf(LRELU(v1)), a1);
    }
    if (j < len) {
      int s0 = __shfl(ev, j);
      float v0 = SCR(s0) + adn;
      u16x8 a0 = ((const u16x8*)xp)[(size_t)s0 * 64 + lane];
      EDGE(__expf(LRELU(v0)), a0);
    }
  }
#undef SCR
#undef EDGE
#undef LRELU

  float rdn = 1.0f / (wsum + 1e-16f);
#pragma unroll
  for (int k = 0; k < 8; ++k) acc[k] *= rdn;

  if (MODE == 1) {
    int c = lane * 8;
    u16x8 rr;
#pragma unroll
    for (int k = 0; k < 8; ++k) {
      float v = acc[k] + bias[c + k];
      v = (v > 0.f) ? v : expm1f(v);
      rr[k] = f2bf(v);
    }
    ((u16x8*)hout)[(size_t)n * 64 + lane] = rr;
  } else {
    // head-mean: channel c'=(lane&15)*8+k lives on lanes {l, l^16, l^32, l^48}
#pragma unroll
    for (int k = 0; k < 8; ++k) {
      float v = acc[k];
      v += __shfl_xor(v, 16);
      v += __shfl_xor(v, 32);
      acc[k] = v * 0.25f + bias[(lane & 15) * 8 + k];
    }
    if (lane < 16) {       // scalar stores: out2 = out+1 is only 4B-aligned
      int cb = lane * 8;
#pragma unroll
      for (int k = 0; k < 8; ++k) out2[(size_t)n * NC2 + cb + k] = acc[k];
    }
    // fused CE: lanes 0..15 hold the 128 logits (copies in upper 48 lanes)
    float mx = acc[0];
#pragma unroll
    for (int k = 1; k < 8; ++k) mx = fmaxf(mx, acc[k]);
#pragma unroll
    for (int o = 1; o < 16; o <<= 1) mx = fmaxf(mx, __shfl_xor(mx, o));
    float e = 0.f;
#pragma unroll
    for (int k = 0; k < 8; ++k) e += __expf(acc[k] - mx);
#pragma unroll
    for (int o = 1; o < 16; o <<= 1) e += __shfl_xor(e, o);
    int yv = y[n];
    float sel = acc[0];
#pragma unroll
    for (int k = 1; k < 8; ++k) sel = ((yv & 7) == k) ? acc[k] : sel;
    float vy = __shfl(sel, yv >> 3);
    if (lane == 0 && msk[n] != 0) {
      float ce = mx + logf(e) - vy;
      int slot = n & 127;
      atomicAdd(&acc2[slot], ce);
      atomicAdd(&acc2[128 + slot], 1.0f);
    }
  }
}

__global__ void k_final(const float* __restrict__ acc2, float* __restrict__ out0) {
  int tid = threadIdx.x;   // 128 threads
  float ce = acc2[tid], ct = acc2[128 + tid];
#pragma unroll
  for (int o = 32; o > 0; o >>= 1) { ce += __shfl_xor(ce, o); ct += __shfl_xor(ct, o); }
  __shared__ float s[4];
  if ((tid & 63) == 0) { s[(tid >> 6) * 2] = ce; s[(tid >> 6) * 2 + 1] = ct; }
  __syncthreads();
  if (tid == 0) out0[0] = (s[0] + s[2]) / (s[1] + s[3]);
}

extern "C" void kernel_launch(void* const* d_in, const int* in_sizes, int n_in,
                              void* d_out, int out_size, void* d_ws, size_t ws_size,
                              hipStream_t stream) {
  const float* x   = (const float*)d_in[0];
  const int*   ei  = (const int*)d_in[1];
  const int*   y   = (const int*)d_in[2];
  const int*   msk = (const int*)d_in[3];
  const float* W1  = (const float*)d_in[4];
  const float* as1 = (const float*)d_in[5];
  const float* ad1 = (const float*)d_in[6];
  const float* b1  = (const float*)d_in[7];
  const float* W2  = (const float*)d_in[8];
  const float* as2 = (const float*)d_in[9];
  const float* ad2 = (const float*)d_in[10];
  const float* b2  = (const float*)d_in[11];
  float* out = (float*)d_out;

  int N = in_sizes[0] / D_IN;   // 20000
  int E = in_sizes[1] / 2;      // 100000
  int Etot = E + N;             // 120000 (self-loops appended)

  float* ws = (float*)d_ws;
  size_t NF = (size_t)N * HC;
  float* asr1 = ws;                       // N*8  (plain-written in GEMM1)
  float* adt1 = asr1 + (size_t)N * NH1;   // N*8
  float* asr2 = adt1 + (size_t)N * NH1;   // N*8  (partials, plain-written GEMM2)
  float* adt2 = asr2 + (size_t)N * 2 * NH2; // N*8
  // ---- zero-init region: acc2, cnt, cursor (contiguous) ----
  float* acc2 = adt2 + (size_t)N * 2 * NH2; // 256
  int*   cnt    = (int*)(acc2 + 256);     // N
  int*   cursor = cnt + N;                // N (zeroed; also pads scan's int4 tail)
  size_t zero_bytes = (256 + 2 * (size_t)N) * sizeof(float);
  // ---- fully-written region ----
  int*   rowstart = cursor + N;           // N+1
  int*   csr_src  = rowstart + N + 1;     // Etot
  ushort* xpbf = (ushort*)((((uintptr_t)(csr_src + Etot)) + 15) & ~(uintptr_t)15);
  ushort* Abf = xpbf + NF;                // N*512
  ushort* Wt1 = Abf + NF;                 // 512*512
  ushort* Wt2 = Wt1 + (size_t)D_IN * HC;  // 512*512

  hipMemsetAsync(acc2, 0, zero_bytes, stream);

  // casts (x) + W tile-transpose + degree histogram in one launch
  int n4x = (int)(NF / 4);
  int nxb = (n4x + 255) / 256;
  int nhb = (Etot + 255) / 256;
  k_pre<<<nxb + 128 + nhb, 256, 0, stream>>>(x, Abf, W1, W2, Wt1, Wt2, n4x,
                                             ei, E, Etot, cnt);

  int nwg = (HC / BN) * ((N + BM - 1) / BM);  // 628
  int aggblocks = (N + 3) / 4;                // 4 nodes (waves) per block

  // ---- layer 1: gemm (blocks 1..628) + CSR scan (block 0) in one launch ----
  k_gemm_bf16<NH1, 1><<<nwg + 1, 256, 0, stream>>>(Abf, Wt1, xpbf, as1, ad1, asr1, adt1, N,
                                                   cnt, rowstart, N);
  k_scatter<<<(Etot + 255) / 256, 256, 0, stream>>>(ei, E, Etot, rowstart, cursor, csr_src);
  k_agg<NH1, 1><<<aggblocks, 256, 0, stream>>>(rowstart, csr_src, asr1, adt1, xpbf, Abf,
                                               nullptr, b1, nullptr, nullptr, nullptr, N);

  // ---- layer 2 ----
  k_gemm_bf16<NH2, 0><<<nwg, 256, 0, stream>>>(Abf, Wt2, xpbf, as2, ad2, asr2, adt2, N,
                                               nullptr, nullptr, N);
  k_agg<NH2, 2><<<aggblocks, 256, 0, stream>>>(rowstart, csr_src, asr2, adt2, xpbf, nullptr,
                                               out + 1, b2, y, msk, acc2, N);

  // ---- epilogue: loss ----
  k_final<<<1, 128, 0, stream>>>(acc2, out);
}